// Round 9
// baseline (334.533 us; speedup 1.0000x reference)
//
#include <hip/hip_runtime.h>

// Problem constants
constexpr int T_ = 16;
constexpr int D_ = 192;
constexpr int H_ = 128;
constexpr int P_ = 128;
constexpr int EC_ = 32;
constexpr int S_ = T_ * D_;  // 3072
constexpr int FF_ = 512;
constexpr float SCALE_ = 0.17677669529663687f;  // 1/sqrt(32)

__device__ __forceinline__ float wave_sum64(float v) {
#pragma unroll
  for (int m = 1; m < 64; m <<= 1) v += __shfl_xor(v, m);
  return v;
}

// ---------------------------------------------------------------------------
// Embed (+ adjacency compaction on blocks < D_, wave 0).
// ---------------------------------------------------------------------------
__global__ __launch_bounds__(128) void embed_adj_kernel(
    const float* __restrict__ x, const float* __restrict__ W_node,
    const float* __restrict__ b_node, const float* __restrict__ time_enc,
    const float* __restrict__ edge_w, float* __restrict__ z,
    int* __restrict__ adj_cnt, int* __restrict__ adj_list) {
  int bx = blockIdx.x;
  int tid = threadIdx.x;
  if (bx < D_ && tid < 64) {  // adjacency row bx
    int lane = tid, cnt = 0;
    for (int base = 0; base < D_; base += 64) {
      int j = base + lane;
      bool pred = (edge_w[bx * D_ + j] > 0.f) || (j == bx);
      unsigned long long mb = __ballot(pred);
      int ofs = __popcll(mb & ((1ull << lane) - 1ull));
      if (pred) adj_list[bx * D_ + cnt + ofs] = j;
      cnt += __popcll(mb);
    }
    if (lane == 0) adj_cnt[bx] = cnt;
  }
  __shared__ float As[8 * H_];
  int m0 = bx * 8;
  for (int idx = tid; idx < 8 * H_; idx += 128) {
    int r = idx >> 7, h = idx & 127;
    int s = m0 + r, t = s / D_, d = s - t * D_;
    As[idx] = x[(t * H_ + h) * D_ + d];
  }
  __syncthreads();
  int j = tid;
  float acc[8];
  float bj = b_node[j];
#pragma unroll
  for (int r = 0; r < 8; ++r) acc[r] = bj;
  for (int h = 0; h < H_; h += 4) {
    float w0 = W_node[(h + 0) * P_ + j], w1 = W_node[(h + 1) * P_ + j];
    float w2 = W_node[(h + 2) * P_ + j], w3 = W_node[(h + 3) * P_ + j];
#pragma unroll
    for (int r = 0; r < 8; ++r) {
      const float4 a = *reinterpret_cast<const float4*>(&As[r * H_ + h]);
      acc[r] = fmaf(a.x, w0, acc[r]);
      acc[r] = fmaf(a.y, w1, acc[r]);
      acc[r] = fmaf(a.z, w2, acc[r]);
      acc[r] = fmaf(a.w, w3, acc[r]);
    }
  }
  float te = time_enc[j];
#pragma unroll
  for (int r = 0; r < 8; ++r) {
    int s = m0 + r;
    z[(size_t)s * P_ + j] = fmaxf(acc[r], 0.f) + te * (float)(s / D_);
  }
}

// ---------------------------------------------------------------------------
// qkv = LN(z; g,b) @ Wqkv + bqkv.  BM=8 rows, NT=384 (CPT=1), grid 384.
// 9 waves/CU (was 2.25).
// ---------------------------------------------------------------------------
__global__ __launch_bounds__(384) void qkv_kernel(
    const float* __restrict__ z, const float* __restrict__ Wqkv,
    const float* __restrict__ bqkv, const float* __restrict__ g,
    const float* __restrict__ b, float* __restrict__ qkvb) {
  constexpr int BM = 8, N = 384;
  int m0 = blockIdx.x * BM;
  int tid = threadIdx.x;
  __shared__ float As[BM * 128];
  {
    float4* As4 = (float4*)As;
    const float4* Z4 = (const float4*)(z + (size_t)m0 * 128);
    if (tid < 256) As4[tid] = Z4[tid];
  }
  __syncthreads();
  {
    int wv = tid >> 6, lane = tid & 63;
    for (int r = wv; r < BM; r += 6) {
      float v0 = As[r * 128 + lane], v1 = As[r * 128 + 64 + lane];
      float s = wave_sum64(v0 + v1);
      float mean = s * (1.f / 128.f);
      float d0 = v0 - mean, d1 = v1 - mean;
      float q = wave_sum64(d0 * d0 + d1 * d1);
      float inv = 1.f / sqrtf(q * (1.f / 128.f) + 1e-5f);
      As[r * 128 + lane] = d0 * inv * g[lane] + b[lane];
      As[r * 128 + 64 + lane] = d1 * inv * g[lane + 64] + b[lane + 64];
    }
  }
  __syncthreads();
  int col = tid;
  float acc[BM];
  float bc = bqkv[col];
#pragma unroll
  for (int r = 0; r < BM; ++r) acc[r] = bc;
  for (int k = 0; k < 128; k += 4) {
    float b0 = Wqkv[(size_t)(k + 0) * N + col];
    float b1 = Wqkv[(size_t)(k + 1) * N + col];
    float b2 = Wqkv[(size_t)(k + 2) * N + col];
    float b3 = Wqkv[(size_t)(k + 3) * N + col];
#pragma unroll
    for (int r = 0; r < BM; ++r) {
      const float4 a = *(const float4*)&As[r * 128 + k];
      acc[r] = fmaf(a.x, b0, acc[r]);
      acc[r] = fmaf(a.y, b1, acc[r]);
      acc[r] = fmaf(a.z, b2, acc[r]);
      acc[r] = fmaf(a.w, b3, acc[r]);
    }
  }
#pragma unroll
  for (int r = 0; r < BM; ++r) qkvb[(size_t)(m0 + r) * N + col] = acc[r];
}

// ---------------------------------------------------------------------------
// Layer tail: attention + Wo + residual + LN2 + FF1 + FF2 + residual.
// 512 thr / 8 rows per block. Attention: 4 groups of 128 threads, 2 queries
// each. z is read once (residual base) and written once (final layer output).
// ---------------------------------------------------------------------------
__global__ __launch_bounds__(512) void tail_kernel(
    const float* __restrict__ qkvb, const int* __restrict__ adj_cnt,
    const int* __restrict__ adj_list, const float* __restrict__ Wo,
    const float* __restrict__ bo, const float* __restrict__ W1,
    const float* __restrict__ b1, const float* __restrict__ W2,
    const float* __restrict__ b2, const float* __restrict__ g2,
    const float* __restrict__ beta2, float* __restrict__ z) {
  constexpr int BM = 8;
  int m0 = blockIdx.x * BM;
  int tid = threadIdx.x;
  __shared__ float att[BM][128];  // 4 KB
  __shared__ float zs[BM][128];   // 4 KB (z after attention residual)
  // union region: attention{klist+scores per group, 8KB x 4} / ffn{mid 16KB + ys 4KB}
  __shared__ __align__(16) unsigned char uA[32768];

  // ---- attention phase: group gq handles rows gq*2+qi ----
  {
    int gq = tid >> 7, lt = tid & 127;
    int h = lt >> 5, dd = lt & 31;
    int* klist = (int*)(uA + gq * 8192);
    float* scores = (float*)(uA + gq * 8192 + 768);
    for (int qi = 0; qi < 2; ++qi) {
      int r = gq * 2 + qi;
      int s = m0 + r;
      int t = s / D_, d1 = s - t * D_;
      int nd2 = adj_cnt[d1];
      __syncthreads();  // protect klist from previous iteration's readers
      for (int kd = lt; kd < nd2; kd += 128) klist[kd] = adj_list[d1 * D_ + kd];
      __syncthreads();  // klist visible to both waves of the group
      int t0 = (t > 0) ? t - 1 : 0;
      int ntp = (t > 0) ? 2 : 1;
      int nk = nd2 * ntp;
      float q = qkvb[(size_t)s * 384 + lt];
      for (int tp = 0; tp < ntp; ++tp) {
        int tt = t0 + tp;
        for (int kd = 0; kd < nd2; ++kd) {
          int sk = tt * D_ + klist[kd];
          float partial = q * qkvb[(size_t)sk * 384 + P_ + lt];
          partial += __shfl_xor(partial, 1);
          partial += __shfl_xor(partial, 2);
          partial += __shfl_xor(partial, 4);
          partial += __shfl_xor(partial, 8);
          partial += __shfl_xor(partial, 16);
          if (dd == 0) scores[h * 384 + tp * nd2 + kd] = partial * SCALE_;
        }
      }
      // softmax within the 32-lane head group (same-wave LDS visibility)
      float mx = -1e30f;
      for (int ki = dd; ki < nk; ki += 32) mx = fmaxf(mx, scores[h * 384 + ki]);
      mx = fmaxf(mx, __shfl_xor(mx, 1));
      mx = fmaxf(mx, __shfl_xor(mx, 2));
      mx = fmaxf(mx, __shfl_xor(mx, 4));
      mx = fmaxf(mx, __shfl_xor(mx, 8));
      mx = fmaxf(mx, __shfl_xor(mx, 16));
      float ssum = 0.f;
      for (int ki = dd; ki < nk; ki += 32) {
        float e = expf(scores[h * 384 + ki] - mx);
        scores[h * 384 + ki] = e;
        ssum += e;
      }
      ssum += __shfl_xor(ssum, 1);
      ssum += __shfl_xor(ssum, 2);
      ssum += __shfl_xor(ssum, 4);
      ssum += __shfl_xor(ssum, 8);
      ssum += __shfl_xor(ssum, 16);
      float inv = 1.f / ssum;
      float acc = 0.f;
      for (int tp = 0; tp < ntp; ++tp) {
        int tt = t0 + tp;
        for (int kd = 0; kd < nd2; ++kd) {
          float aev = scores[h * 384 + tp * nd2 + kd];
          int sk = tt * D_ + klist[kd];
          acc = fmaf(aev, qkvb[(size_t)sk * 384 + 2 * P_ + lt], acc);
        }
      }
      att[r][lt] = acc * inv;
    }
  }
  __syncthreads();  // att complete; attention LDS region dead

  // ---- Wo + residual -> zs (and nothing to global yet) ----
  {
    int col = tid & 127, rg = tid >> 7;
    int r0 = rg * 2;
    float p0 = 0.f, p1 = 0.f;
    for (int k = 0; k < 128; k += 4) {
      float w0 = Wo[(size_t)(k + 0) * P_ + col];
      float w1 = Wo[(size_t)(k + 1) * P_ + col];
      float w2 = Wo[(size_t)(k + 2) * P_ + col];
      float w3 = Wo[(size_t)(k + 3) * P_ + col];
      const float4 a0 = *(const float4*)&att[r0][k];
      const float4 a1 = *(const float4*)&att[r0 + 1][k];
      p0 = fmaf(a0.x, w0, p0); p0 = fmaf(a0.y, w1, p0);
      p0 = fmaf(a0.z, w2, p0); p0 = fmaf(a0.w, w3, p0);
      p1 = fmaf(a1.x, w0, p1); p1 = fmaf(a1.y, w1, p1);
      p1 = fmaf(a1.z, w2, p1); p1 = fmaf(a1.w, w3, p1);
    }
    float bb = bo[col];
    zs[r0][col] = z[(size_t)(m0 + r0) * P_ + col] + p0 + bb;
    zs[r0 + 1][col] = z[(size_t)(m0 + r0 + 1) * P_ + col] + p1 + bb;
  }
  __syncthreads();

  float* mid = (float*)uA;            // [8][512] 16 KB
  float* ys = (float*)(uA + 16384);   // [8][128] 4 KB

  // ---- LN2: one wave per row ----
  {
    int wv = tid >> 6, lane = tid & 63;
    float v0 = zs[wv][lane], v1 = zs[wv][lane + 64];
    float ssm = wave_sum64(v0 + v1);
    float mean = ssm * (1.f / 128.f);
    float d0 = v0 - mean, d1 = v1 - mean;
    float qv = wave_sum64(d0 * d0 + d1 * d1);
    float inv = 1.f / sqrtf(qv * (1.f / 128.f) + 1e-5f);
    ys[wv * 128 + lane] = d0 * inv * g2[lane] + beta2[lane];
    ys[wv * 128 + lane + 64] = d1 * inv * g2[lane + 64] + beta2[lane + 64];
  }
  __syncthreads();

  // ---- FF1: one col per thread (512 cols) ----
  {
    int col = tid;
    float acc[8];
    float bb = b1[col];
#pragma unroll
    for (int r = 0; r < 8; ++r) acc[r] = bb;
    for (int k = 0; k < 128; k += 4) {
      float w0 = W1[(size_t)(k + 0) * FF_ + col];
      float w1 = W1[(size_t)(k + 1) * FF_ + col];
      float w2 = W1[(size_t)(k + 2) * FF_ + col];
      float w3 = W1[(size_t)(k + 3) * FF_ + col];
#pragma unroll
      for (int r = 0; r < 8; ++r) {
        const float4 a = *(const float4*)&ys[r * 128 + k];
        acc[r] = fmaf(a.x, w0, acc[r]);
        acc[r] = fmaf(a.y, w1, acc[r]);
        acc[r] = fmaf(a.z, w2, acc[r]);
        acc[r] = fmaf(a.w, w3, acc[r]);
      }
    }
#pragma unroll
    for (int r = 0; r < 8; ++r) mid[r * FF_ + col] = fmaxf(acc[r], 0.f);
  }
  __syncthreads();

  // ---- FF2 + residual -> z (final layer output) ----
  {
    int col = tid & 127, rg = tid >> 7;
    int r0 = rg * 2;
    float a0 = 0.f, a1 = 0.f;
    for (int k = 0; k < FF_; k += 4) {
      float w0 = W2[(size_t)(k + 0) * P_ + col];
      float w1 = W2[(size_t)(k + 1) * P_ + col];
      float w2 = W2[(size_t)(k + 2) * P_ + col];
      float w3 = W2[(size_t)(k + 3) * P_ + col];
      const float4 m0v = *(const float4*)&mid[r0 * FF_ + k];
      const float4 m1v = *(const float4*)&mid[(r0 + 1) * FF_ + k];
      a0 = fmaf(m0v.x, w0, a0); a0 = fmaf(m0v.y, w1, a0);
      a0 = fmaf(m0v.z, w2, a0); a0 = fmaf(m0v.w, w3, a0);
      a1 = fmaf(m1v.x, w0, a1); a1 = fmaf(m1v.y, w1, a1);
      a1 = fmaf(m1v.z, w2, a1); a1 = fmaf(m1v.w, w3, a1);
    }
    float bb = b2[col];
    z[(size_t)(m0 + r0) * P_ + col] = zs[r0][col] + a0 + bb;
    z[(size_t)(m0 + r0 + 1) * P_ + col] = zs[r0 + 1][col] + a1 + bb;
  }
}

// ---------------------------------------------------------------------------
// pre = z @ [Wc1[:P] | Wc1[P:2P] | Wd1[:P] | Wd1[P:]]  (N=512, CPT=1, NT=512)
// ---------------------------------------------------------------------------
__global__ __launch_bounds__(512) void pre_gemm_kernel(
    const float* __restrict__ A, const float* __restrict__ Wc1,
    const float* __restrict__ Wd1, float* __restrict__ pre) {
  constexpr int K = 128, BM = 8;
  int m0 = blockIdx.x * BM;
  int tid = threadIdx.x;
  __shared__ float As[BM * K];
  {
    float4* As4 = (float4*)As;
    const float4* A4 = (const float4*)(A + (size_t)m0 * K);
    if (tid < 256) As4[tid] = A4[tid];
  }
  __syncthreads();
  int col = tid;
  int seg = col >> 7, cc = col & 127;
  const float* Bbase = (seg < 2 ? Wc1 : Wd1) + ((seg & 1) ? P_ * P_ : 0) + cc;
  float acc[BM];
#pragma unroll
  for (int r = 0; r < BM; ++r) acc[r] = 0.f;
  for (int k = 0; k < K; k += 4) {
    float b0 = Bbase[(size_t)(k + 0) * P_];
    float b1 = Bbase[(size_t)(k + 1) * P_];
    float b2 = Bbase[(size_t)(k + 2) * P_];
    float b3 = Bbase[(size_t)(k + 3) * P_];
#pragma unroll
    for (int r = 0; r < BM; ++r) {
      const float4 a = *(const float4*)&As[r * K + k];
      acc[r] = fmaf(a.x, b0, acc[r]);
      acc[r] = fmaf(a.y, b1, acc[r]);
      acc[r] = fmaf(a.z, b2, acc[r]);
      acc[r] = fmaf(a.w, b3, acc[r]);
    }
  }
#pragma unroll
  for (int r = 0; r < BM; ++r) pre[(size_t)(m0 + r) * 512 + col] = acc[r];
}

// ---------------------------------------------------------------------------
// Logits (active entries; full -1e9 fill) + dist epilogue. grid (D_, T_-1).
// ---------------------------------------------------------------------------
__global__ __launch_bounds__(64) void logits_dist_kernel(
    const float* __restrict__ pre, const int* __restrict__ adj_cnt,
    const int* __restrict__ adj_list, const float* __restrict__ edge_w,
    const float* __restrict__ W_edge, const float* __restrict__ b_edge,
    const float* __restrict__ Wc1e, const float* __restrict__ bc1,
    const float* __restrict__ Wc2, const float* __restrict__ bc2,
    const float* __restrict__ bd1, const float* __restrict__ Wd2,
    const float* __restrict__ bd2, float* __restrict__ logits,
    float* __restrict__ dist) {
  int i = blockIdx.x;
  int t = blockIdx.y;
  int lane = threadIdx.x;
  int w = t * D_ + i;
  float* lrow = logits + (size_t)w * D_;
  for (int j = lane; j < D_; j += 64) lrow[j] = -1e9f;

  const float* hnr = pre + (size_t)((t + 1) * D_ + i) * 512;
  float hn0 = hnr[lane], hn1 = hnr[lane + 64];
  float bc1_0 = bc1[lane], bc1_1 = bc1[lane + 64];
  float wc0 = Wc2[lane], wc1 = Wc2[lane + 64];
  float bb = bc2[0];
  int cnt = adj_cnt[i];
  for (int jj = 0; jj < cnt; ++jj) {
    int j = adj_list[i * D_ + jj];
    float wv = edge_w[i * D_ + j];
    float he0 = 0.f, he1 = 0.f;
#pragma unroll 8
    for (int e = 0; e < EC_; ++e) {
      float enc = fmaxf(fmaf(wv, W_edge[e], b_edge[e]), 0.f);
      he0 = fmaf(enc, Wc1e[e * P_ + lane], he0);
      he1 = fmaf(enc, Wc1e[e * P_ + lane + 64], he1);
    }
    const float* hcr = pre + (size_t)(t * D_ + j) * 512 + 128;
    float sacc = fmaxf(hn0 + hcr[lane] + he0 + bc1_0, 0.f) * wc0 +
                 fmaxf(hn1 + hcr[lane + 64] + he1 + bc1_1, 0.f) * wc1;
    sacc = wave_sum64(sacc);
    if (lane == 0) lrow[j] = sacc + bb;
  }

  const float* ar = pre + (size_t)w * 512 + 256;
  const float* br = pre + (size_t)(w + D_) * 512 + 384;
  float v0 = fmaxf(ar[lane] + br[lane] + bd1[lane], 0.f) * Wd2[lane];
  float v1 = fmaxf(ar[lane + 64] + br[lane + 64] + bd1[lane + 64], 0.f) * Wd2[lane + 64];
  float sd = wave_sum64(v0 + v1);
  if (lane == 0) dist[w] = sd + bd2[0];
}

// ---------------------------------------------------------------------------
extern "C" void kernel_launch(void* const* d_in, const int* in_sizes, int n_in,
                              void* d_out, int out_size, void* d_ws,
                              size_t ws_size, hipStream_t stream) {
  const float* x = (const float*)d_in[0];
  const float* edge_w = (const float*)d_in[1];
  const float* W_node = (const float*)d_in[2];
  const float* b_node = (const float*)d_in[3];
  const float* W_edge = (const float*)d_in[4];
  const float* b_edge = (const float*)d_in[5];
  const float* time_enc = (const float*)d_in[6];
  const float* Wqkv = (const float*)d_in[7];
  const float* bqkv = (const float*)d_in[8];
  const float* Wo = (const float*)d_in[9];
  const float* bo = (const float*)d_in[10];
  const float* W1 = (const float*)d_in[11];
  const float* b1 = (const float*)d_in[12];
  const float* W2 = (const float*)d_in[13];
  const float* b2 = (const float*)d_in[14];
  const float* g1 = (const float*)d_in[15];
  const float* beta1 = (const float*)d_in[16];
  const float* g2 = (const float*)d_in[17];
  const float* beta2 = (const float*)d_in[18];
  const float* Wc1 = (const float*)d_in[19];
  const float* bc1 = (const float*)d_in[20];
  const float* Wc2 = (const float*)d_in[21];
  const float* bc2 = (const float*)d_in[22];
  const float* Wd1 = (const float*)d_in[23];
  const float* bd1 = (const float*)d_in[24];
  const float* Wd2 = (const float*)d_in[25];
  const float* bd2 = (const float*)d_in[26];

  float* ws = (float*)d_ws;
  float* z = ws;                   // S*128
  float* qkvb = z + S_ * 128;      // S*384
  float* pre = qkvb + S_ * 384;    // S*512
  int* adj_cnt = (int*)(pre + S_ * 512);  // D_
  int* adj_list = adj_cnt + D_;           // D_*D_

  float* logits = (float*)d_out;
  float* dist = (float*)d_out + (T_ - 1) * D_ * D_;

  embed_adj_kernel<<<S_ / 8, 128, 0, stream>>>(x, W_node, b_node, time_enc,
                                               edge_w, z, adj_cnt, adj_list);
  for (int it = 0; it < 2; ++it) {
    qkv_kernel<<<S_ / 8, 384, 0, stream>>>(z, Wqkv, bqkv, g1, beta1, qkvb);
    tail_kernel<<<S_ / 8, 512, 0, stream>>>(qkvb, adj_cnt, adj_list, Wo, bo,
                                            W1, b1, W2, b2, g2, beta2, z);
  }
  pre_gemm_kernel<<<S_ / 8, 512, 0, stream>>>(z, Wc1, Wd1, pre);
  logits_dist_kernel<<<dim3(D_, T_ - 1), 64, 0, stream>>>(
      pre, adj_cnt, adj_list, edge_w, W_edge, b_edge, Wc1 + 2 * P_ * P_, bc1,
      Wc2, bc2, bd1, Wd2, bd2, logits, dist);
}

// Round 11
// 295.448 us; speedup vs baseline: 1.1323x; 1.1323x over previous
//
#include <hip/hip_runtime.h>

// Problem constants
constexpr int T_ = 16;
constexpr int D_ = 192;
constexpr int H_ = 128;
constexpr int P_ = 128;
constexpr int EC_ = 32;
constexpr int S_ = T_ * D_;  // 3072
constexpr int FF_ = 512;
constexpr float SCALE_ = 0.17677669529663687f;  // 1/sqrt(32)

__device__ __forceinline__ float wave_sum64(float v) {
#pragma unroll
  for (int m = 1; m < 64; m <<= 1) v += __shfl_xor(v, m);
  return v;
}

// ---------------------------------------------------------------------------
// Embed, BM=4 (+ adjacency compaction on blocks < D_, wave 0).
// ---------------------------------------------------------------------------
__global__ __launch_bounds__(128) void embed_adj_kernel(
    const float* __restrict__ x, const float* __restrict__ W_node,
    const float* __restrict__ b_node, const float* __restrict__ time_enc,
    const float* __restrict__ edge_w, float* __restrict__ z,
    int* __restrict__ adj_cnt, int* __restrict__ adj_list) {
  int bx = blockIdx.x;
  int tid = threadIdx.x;
  if (bx < D_ && tid < 64) {  // adjacency row bx
    int lane = tid, cnt = 0;
    for (int base = 0; base < D_; base += 64) {
      int j = base + lane;
      bool pred = (edge_w[bx * D_ + j] > 0.f) || (j == bx);
      unsigned long long mb = __ballot(pred);
      int ofs = __popcll(mb & ((1ull << lane) - 1ull));
      if (pred) adj_list[bx * D_ + cnt + ofs] = j;
      cnt += __popcll(mb);
    }
    if (lane == 0) adj_cnt[bx] = cnt;
  }
  __shared__ float As[4 * H_];
  int m0 = bx * 4;
  for (int idx = tid; idx < 4 * H_; idx += 128) {
    int r = idx >> 7, h = idx & 127;
    int s = m0 + r, t = s / D_, d = s - t * D_;
    As[idx] = x[(t * H_ + h) * D_ + d];
  }
  __syncthreads();
  int j = tid;
  float acc[4];
  float bj = b_node[j];
#pragma unroll
  for (int r = 0; r < 4; ++r) acc[r] = bj;
  for (int h = 0; h < H_; h += 4) {
    float w0 = W_node[(h + 0) * P_ + j], w1 = W_node[(h + 1) * P_ + j];
    float w2 = W_node[(h + 2) * P_ + j], w3 = W_node[(h + 3) * P_ + j];
#pragma unroll
    for (int r = 0; r < 4; ++r) {
      const float4 a = *reinterpret_cast<const float4*>(&As[r * H_ + h]);
      acc[r] = fmaf(a.x, w0, acc[r]);
      acc[r] = fmaf(a.y, w1, acc[r]);
      acc[r] = fmaf(a.z, w2, acc[r]);
      acc[r] = fmaf(a.w, w3, acc[r]);
    }
  }
  float te = time_enc[j];
#pragma unroll
  for (int r = 0; r < 4; ++r) {
    int s = m0 + r;
    z[(size_t)s * P_ + j] = fmaxf(acc[r], 0.f) + te * (float)(s / D_);
  }
}

// ---------------------------------------------------------------------------
// qkv = LN(z; g,b) @ Wqkv + bqkv.  BM=4, NT=384, grid 768 (18 waves/CU).
// ---------------------------------------------------------------------------
__global__ __launch_bounds__(384) void qkv_kernel(
    const float* __restrict__ z, const float* __restrict__ Wqkv,
    const float* __restrict__ bqkv, const float* __restrict__ g,
    const float* __restrict__ b, float* __restrict__ qkvb) {
  constexpr int BM = 4, N = 384;
  int m0 = blockIdx.x * BM;
  int tid = threadIdx.x;
  __shared__ float As[BM * 128];
  {
    float4* As4 = (float4*)As;
    const float4* Z4 = (const float4*)(z + (size_t)m0 * 128);
    if (tid < BM * 32) As4[tid] = Z4[tid];
  }
  __syncthreads();
  {
    int wv = tid >> 6, lane = tid & 63;
    if (wv < BM) {
      int r = wv;
      float v0 = As[r * 128 + lane], v1 = As[r * 128 + 64 + lane];
      float s = wave_sum64(v0 + v1);
      float mean = s * (1.f / 128.f);
      float d0 = v0 - mean, d1 = v1 - mean;
      float q = wave_sum64(d0 * d0 + d1 * d1);
      float inv = 1.f / sqrtf(q * (1.f / 128.f) + 1e-5f);
      As[r * 128 + lane] = d0 * inv * g[lane] + b[lane];
      As[r * 128 + 64 + lane] = d1 * inv * g[lane + 64] + b[lane + 64];
    }
  }
  __syncthreads();
  int col = tid;
  float acc[BM];
  float bc = bqkv[col];
#pragma unroll
  for (int r = 0; r < BM; ++r) acc[r] = bc;
  for (int k = 0; k < 128; k += 4) {
    float b0 = Wqkv[(size_t)(k + 0) * N + col];
    float b1 = Wqkv[(size_t)(k + 1) * N + col];
    float b2 = Wqkv[(size_t)(k + 2) * N + col];
    float b3 = Wqkv[(size_t)(k + 3) * N + col];
#pragma unroll
    for (int r = 0; r < BM; ++r) {
      const float4 a = *(const float4*)&As[r * 128 + k];
      acc[r] = fmaf(a.x, b0, acc[r]);
      acc[r] = fmaf(a.y, b1, acc[r]);
      acc[r] = fmaf(a.z, b2, acc[r]);
      acc[r] = fmaf(a.w, b3, acc[r]);
    }
  }
#pragma unroll
  for (int r = 0; r < BM; ++r) qkvb[(size_t)(m0 + r) * N + col] = acc[r];
}

// ---------------------------------------------------------------------------
// Sparse attention + Wo projection + residual. One block (128 thr) per query.
// Key loops manually unrolled x2 for memory-level parallelism.
// ---------------------------------------------------------------------------
__global__ __launch_bounds__(128) void attn_wo_kernel(
    const float* __restrict__ qkvb, const int* __restrict__ adj_cnt,
    const int* __restrict__ adj_list, const float* __restrict__ Wo,
    const float* __restrict__ bo, float* __restrict__ z) {
  int s = blockIdx.x;
  int t = s / D_, d1 = s - t * D_;
  int tid = threadIdx.x;
  __shared__ int klist[D_];
  __shared__ float scores[4][2 * D_];
  __shared__ float att[128];

  int nd2 = adj_cnt[d1];
  for (int kd = tid; kd < nd2; kd += 128) klist[kd] = adj_list[d1 * D_ + kd];
  __syncthreads();
  int t0 = (t > 0) ? t - 1 : 0;
  int ntp = (t > 0) ? 2 : 1;
  int nk = nd2 * ntp;

  float q = qkvb[(size_t)s * 384 + tid];
  int h = tid >> 5, dd = tid & 31;

  for (int tp = 0; tp < ntp; ++tp) {
    int tt = t0 + tp;
    int kd = 0;
    for (; kd + 2 <= nd2; kd += 2) {  // 2-way unroll: 2 loads in flight
      int sk0 = tt * D_ + klist[kd];
      int sk1 = tt * D_ + klist[kd + 1];
      float p0 = q * qkvb[(size_t)sk0 * 384 + P_ + tid];
      float p1 = q * qkvb[(size_t)sk1 * 384 + P_ + tid];
#pragma unroll
      for (int m = 1; m < 32; m <<= 1) {
        p0 += __shfl_xor(p0, m);
        p1 += __shfl_xor(p1, m);
      }
      if (dd == 0) {
        scores[h][tp * nd2 + kd] = p0 * SCALE_;
        scores[h][tp * nd2 + kd + 1] = p1 * SCALE_;
      }
    }
    if (kd < nd2) {
      int sk = tt * D_ + klist[kd];
      float p = q * qkvb[(size_t)sk * 384 + P_ + tid];
#pragma unroll
      for (int m = 1; m < 32; m <<= 1) p += __shfl_xor(p, m);
      if (dd == 0) scores[h][tp * nd2 + kd] = p * SCALE_;
    }
  }
  // same-wave LDS visibility: head h's scores written by this wave
  float mx = -1e30f;
  for (int ki = dd; ki < nk; ki += 32) mx = fmaxf(mx, scores[h][ki]);
#pragma unroll
  for (int m = 1; m < 32; m <<= 1) mx = fmaxf(mx, __shfl_xor(mx, m));
  float ssum = 0.f;
  for (int ki = dd; ki < nk; ki += 32) {
    float e = expf(scores[h][ki] - mx);
    scores[h][ki] = e;
    ssum += e;
  }
#pragma unroll
  for (int m = 1; m < 32; m <<= 1) ssum += __shfl_xor(ssum, m);
  float inv = 1.f / ssum;

  float acc = 0.f;
  for (int tp = 0; tp < ntp; ++tp) {
    int tt = t0 + tp;
    int kd = 0;
    for (; kd + 2 <= nd2; kd += 2) {  // 2-way unroll
      float e0 = scores[h][tp * nd2 + kd];
      float e1 = scores[h][tp * nd2 + kd + 1];
      int sk0 = tt * D_ + klist[kd];
      int sk1 = tt * D_ + klist[kd + 1];
      float v0 = qkvb[(size_t)sk0 * 384 + 2 * P_ + tid];
      float v1 = qkvb[(size_t)sk1 * 384 + 2 * P_ + tid];
      acc = fmaf(e0, v0, acc);
      acc = fmaf(e1, v1, acc);
    }
    if (kd < nd2) {
      float e = scores[h][tp * nd2 + kd];
      int sk = tt * D_ + klist[kd];
      acc = fmaf(e, qkvb[(size_t)sk * 384 + 2 * P_ + tid], acc);
    }
  }
  att[tid] = acc * inv;
  __syncthreads();

  // Wo projection + residual
  int c = tid;
  float p = 0.f;
  for (int k = 0; k < 128; k += 4) {
    const float4 a = *(const float4*)&att[k];
    p = fmaf(a.x, Wo[(size_t)(k + 0) * P_ + c], p);
    p = fmaf(a.y, Wo[(size_t)(k + 1) * P_ + c], p);
    p = fmaf(a.z, Wo[(size_t)(k + 2) * P_ + c], p);
    p = fmaf(a.w, Wo[(size_t)(k + 3) * P_ + c], p);
  }
  z[(size_t)s * P_ + c] += p + bo[c];
}

// ---------------------------------------------------------------------------
// Fused FFN: z += relu(LN(z;g2,beta2) @ W1 + b1) @ W2 + b2.
// BM=4, NT=256, grid 768 (12 waves/CU). LN in-place in As; mid in LDS.
// ---------------------------------------------------------------------------
__global__ __launch_bounds__(256) void ffn_kernel(
    const float* __restrict__ W1, const float* __restrict__ b1,
    const float* __restrict__ W2, const float* __restrict__ b2,
    const float* __restrict__ g, const float* __restrict__ b,
    float* __restrict__ z) {
  constexpr int BM = 4, NT = 256;
  int m0 = blockIdx.x * BM;
  int tid = threadIdx.x;
  __shared__ float As[BM * 128];
  __shared__ float mid[BM * FF_];
  {
    float4* As4 = (float4*)As;
    const float4* Z4 = (const float4*)(z + (size_t)m0 * 128);
    if (tid < BM * 32) As4[tid] = Z4[tid];
  }
  __syncthreads();
  {
    int wv = tid >> 6, lane = tid & 63;
    float v0 = As[wv * 128 + lane], v1 = As[wv * 128 + 64 + lane];
    float s = wave_sum64(v0 + v1);
    float mean = s * (1.f / 128.f);
    float d0 = v0 - mean, d1 = v1 - mean;
    float qv = wave_sum64(d0 * d0 + d1 * d1);
    float inv = 1.f / sqrtf(qv * (1.f / 128.f) + 1e-5f);
    As[wv * 128 + lane] = d0 * inv * g[lane] + b[lane];
    As[wv * 128 + lane + 64] = d1 * inv * g[lane + 64] + b[lane + 64];
  }
  __syncthreads();
  {  // FF1: CPT=2 (cols 2*tid, 2*tid+1), float2 weight loads
    int c0 = 2 * tid;
    float acc0[BM], acc1[BM];
    float bb0 = b1[c0], bb1 = b1[c0 + 1];
#pragma unroll
    for (int r = 0; r < BM; ++r) {
      acc0[r] = bb0;
      acc1[r] = bb1;
    }
    for (int k = 0; k < 128; k += 4) {
      float2 bv0 = *(const float2*)(W1 + (size_t)(k + 0) * FF_ + c0);
      float2 bv1 = *(const float2*)(W1 + (size_t)(k + 1) * FF_ + c0);
      float2 bv2 = *(const float2*)(W1 + (size_t)(k + 2) * FF_ + c0);
      float2 bv3 = *(const float2*)(W1 + (size_t)(k + 3) * FF_ + c0);
#pragma unroll
      for (int r = 0; r < BM; ++r) {
        const float4 a = *(const float4*)&As[r * 128 + k];
        acc0[r] = fmaf(a.x, bv0.x, acc0[r]);
        acc1[r] = fmaf(a.x, bv0.y, acc1[r]);
        acc0[r] = fmaf(a.y, bv1.x, acc0[r]);
        acc1[r] = fmaf(a.y, bv1.y, acc1[r]);
        acc0[r] = fmaf(a.z, bv2.x, acc0[r]);
        acc1[r] = fmaf(a.z, bv2.y, acc1[r]);
        acc0[r] = fmaf(a.w, bv3.x, acc0[r]);
        acc1[r] = fmaf(a.w, bv3.y, acc1[r]);
      }
    }
#pragma unroll
    for (int r = 0; r < BM; ++r) {
      mid[r * FF_ + c0] = fmaxf(acc0[r], 0.f);
      mid[r * FF_ + c0 + 1] = fmaxf(acc1[r], 0.f);
    }
  }
  __syncthreads();
  {  // FF2 + residual: 2 rowgroups x 128 cols, 2 rows each
    int rg = tid >> 7, col = tid & 127;
    int r0 = rg * 2;
    float a0 = 0.f, a1 = 0.f;
    for (int k = 0; k < FF_; k += 4) {
      float w0 = W2[(size_t)(k + 0) * P_ + col];
      float w1 = W2[(size_t)(k + 1) * P_ + col];
      float w2 = W2[(size_t)(k + 2) * P_ + col];
      float w3 = W2[(size_t)(k + 3) * P_ + col];
      const float4 m0v = *(const float4*)&mid[r0 * FF_ + k];
      const float4 m1v = *(const float4*)&mid[(r0 + 1) * FF_ + k];
      a0 = fmaf(m0v.x, w0, a0); a0 = fmaf(m0v.y, w1, a0);
      a0 = fmaf(m0v.z, w2, a0); a0 = fmaf(m0v.w, w3, a0);
      a1 = fmaf(m1v.x, w0, a1); a1 = fmaf(m1v.y, w1, a1);
      a1 = fmaf(m1v.z, w2, a1); a1 = fmaf(m1v.w, w3, a1);
    }
    float bb = b2[col];
    z[(size_t)(m0 + r0) * P_ + col] += a0 + bb;
    z[(size_t)(m0 + r0 + 1) * P_ + col] += a1 + bb;
  }
}

// ---------------------------------------------------------------------------
// pre = z @ [Wc1[:P] | Wc1[P:2P] | Wd1[:P] | Wd1[P:]]  (N=512, CPT=1, NT=512)
// ---------------------------------------------------------------------------
__global__ __launch_bounds__(512) void pre_gemm_kernel(
    const float* __restrict__ A, const float* __restrict__ Wc1,
    const float* __restrict__ Wd1, float* __restrict__ pre) {
  constexpr int K = 128, BM = 8;
  int m0 = blockIdx.x * BM;
  int tid = threadIdx.x;
  __shared__ float As[BM * K];
  {
    float4* As4 = (float4*)As;
    const float4* A4 = (const float4*)(A + (size_t)m0 * K);
    if (tid < 256) As4[tid] = A4[tid];
  }
  __syncthreads();
  int col = tid;
  int seg = col >> 7, cc = col & 127;
  const float* Bbase = (seg < 2 ? Wc1 : Wd1) + ((seg & 1) ? P_ * P_ : 0) + cc;
  float acc[BM];
#pragma unroll
  for (int r = 0; r < BM; ++r) acc[r] = 0.f;
  for (int k = 0; k < K; k += 4) {
    float b0 = Bbase[(size_t)(k + 0) * P_];
    float b1 = Bbase[(size_t)(k + 1) * P_];
    float b2 = Bbase[(size_t)(k + 2) * P_];
    float b3 = Bbase[(size_t)(k + 3) * P_];
#pragma unroll
    for (int r = 0; r < BM; ++r) {
      const float4 a = *(const float4*)&As[r * K + k];
      acc[r] = fmaf(a.x, b0, acc[r]);
      acc[r] = fmaf(a.y, b1, acc[r]);
      acc[r] = fmaf(a.z, b2, acc[r]);
      acc[r] = fmaf(a.w, b3, acc[r]);
    }
  }
#pragma unroll
  for (int r = 0; r < BM; ++r) pre[(size_t)(m0 + r) * 512 + col] = acc[r];
}

// ---------------------------------------------------------------------------
// Logits (active entries; full -1e9 fill) + dist epilogue. grid (D_, T_-1).
// ---------------------------------------------------------------------------
__global__ __launch_bounds__(64) void logits_dist_kernel(
    const float* __restrict__ pre, const int* __restrict__ adj_cnt,
    const int* __restrict__ adj_list, const float* __restrict__ edge_w,
    const float* __restrict__ W_edge, const float* __restrict__ b_edge,
    const float* __restrict__ Wc1e, const float* __restrict__ bc1,
    const float* __restrict__ Wc2, const float* __restrict__ bc2,
    const float* __restrict__ bd1, const float* __restrict__ Wd2,
    const float* __restrict__ bd2, float* __restrict__ logits,
    float* __restrict__ dist) {
  int i = blockIdx.x;
  int t = blockIdx.y;
  int lane = threadIdx.x;
  int w = t * D_ + i;
  float* lrow = logits + (size_t)w * D_;
  for (int j = lane; j < D_; j += 64) lrow[j] = -1e9f;

  const float* hnr = pre + (size_t)((t + 1) * D_ + i) * 512;
  float hn0 = hnr[lane], hn1 = hnr[lane + 64];
  float bc1_0 = bc1[lane], bc1_1 = bc1[lane + 64];
  float wc0 = Wc2[lane], wc1 = Wc2[lane + 64];
  float bb = bc2[0];
  int cnt = adj_cnt[i];
  for (int jj = 0; jj < cnt; ++jj) {
    int j = adj_list[i * D_ + jj];
    float wv = edge_w[i * D_ + j];
    float he0 = 0.f, he1 = 0.f;
#pragma unroll 8
    for (int e = 0; e < EC_; ++e) {
      float enc = fmaxf(fmaf(wv, W_edge[e], b_edge[e]), 0.f);
      he0 = fmaf(enc, Wc1e[e * P_ + lane], he0);
      he1 = fmaf(enc, Wc1e[e * P_ + lane + 64], he1);
    }
    const float* hcr = pre + (size_t)(t * D_ + j) * 512 + 128;
    float sacc = fmaxf(hn0 + hcr[lane] + he0 + bc1_0, 0.f) * wc0 +
                 fmaxf(hn1 + hcr[lane + 64] + he1 + bc1_1, 0.f) * wc1;
    sacc = wave_sum64(sacc);
    if (lane == 0) lrow[j] = sacc + bb;
  }

  const float* ar = pre + (size_t)w * 512 + 256;
  const float* br = pre + (size_t)(w + D_) * 512 + 384;
  float v0 = fmaxf(ar[lane] + br[lane] + bd1[lane], 0.f) * Wd2[lane];
  float v1 = fmaxf(ar[lane + 64] + br[lane + 64] + bd1[lane + 64], 0.f) * Wd2[lane + 64];
  float sd = wave_sum64(v0 + v1);
  if (lane == 0) dist[w] = sd + bd2[0];
}

// ---------------------------------------------------------------------------
extern "C" void kernel_launch(void* const* d_in, const int* in_sizes, int n_in,
                              void* d_out, int out_size, void* d_ws,
                              size_t ws_size, hipStream_t stream) {
  const float* x = (const float*)d_in[0];
  const float* edge_w = (const float*)d_in[1];
  const float* W_node = (const float*)d_in[2];
  const float* b_node = (const float*)d_in[3];
  const float* W_edge = (const float*)d_in[4];
  const float* b_edge = (const float*)d_in[5];
  const float* time_enc = (const float*)d_in[6];
  const float* Wqkv = (const float*)d_in[7];
  const float* bqkv = (const float*)d_in[8];
  const float* Wo = (const float*)d_in[9];
  const float* bo = (const float*)d_in[10];
  const float* W1 = (const float*)d_in[11];
  const float* b1 = (const float*)d_in[12];
  const float* W2 = (const float*)d_in[13];
  const float* b2 = (const float*)d_in[14];
  const float* g1 = (const float*)d_in[15];
  const float* beta1 = (const float*)d_in[16];
  const float* g2 = (const float*)d_in[17];
  const float* beta2 = (const float*)d_in[18];
  const float* Wc1 = (const float*)d_in[19];
  const float* bc1 = (const float*)d_in[20];
  const float* Wc2 = (const float*)d_in[21];
  const float* bc2 = (const float*)d_in[22];
  const float* Wd1 = (const float*)d_in[23];
  const float* bd1 = (const float*)d_in[24];
  const float* Wd2 = (const float*)d_in[25];
  const float* bd2 = (const float*)d_in[26];

  float* ws = (float*)d_ws;
  float* z = ws;                   // S*128
  float* qkvb = z + S_ * 128;      // S*384
  float* pre = qkvb + S_ * 384;    // S*512
  int* adj_cnt = (int*)(pre + S_ * 512);  // D_
  int* adj_list = adj_cnt + D_;           // D_*D_

  float* logits = (float*)d_out;
  float* dist = (float*)d_out + (T_ - 1) * D_ * D_;

  embed_adj_kernel<<<S_ / 4, 128, 0, stream>>>(x, W_node, b_node, time_enc,
                                               edge_w, z, adj_cnt, adj_list);
  for (int it = 0; it < 2; ++it) {
    qkv_kernel<<<S_ / 4, 384, 0, stream>>>(z, Wqkv, bqkv, g1, beta1, qkvb);
    attn_wo_kernel<<<S_, 128, 0, stream>>>(qkvb, adj_cnt, adj_list, Wo, bo, z);
    ffn_kernel<<<S_ / 4, 256, 0, stream>>>(W1, b1, W2, b2, g2, beta2, z);
  }
  pre_gemm_kernel<<<S_ / 8, 512, 0, stream>>>(z, Wc1, Wd1, pre);
  logits_dist_kernel<<<dim3(D_, T_ - 1), 64, 0, stream>>>(
      pre, adj_cnt, adj_list, edge_w, W_edge, b_edge, Wc1 + 2 * P_ * P_, bc1,
      Wc2, bc2, bd1, Wd2, bd2, logits, dist);
}